// Round 2
// baseline (202.794 us; speedup 1.0000x reference)
//
#include <hip/hip_runtime.h>

typedef short bf16x8 __attribute__((ext_vector_type(8)));
typedef float f32x4 __attribute__((ext_vector_type(4)));
typedef unsigned short us4 __attribute__((ext_vector_type(4)));
typedef unsigned short us8 __attribute__((ext_vector_type(8)));

#define MFMA16(a, b, c) __builtin_amdgcn_mfma_f32_16x16x32_bf16(a, b, c, 0, 0, 0)

__device__ __forceinline__ unsigned short f2bf(float f) {
    unsigned int u = __float_as_uint(f);
    u += 0x7FFFu + ((u >> 16) & 1u);   // round-to-nearest-even
    return (unsigned short)(u >> 16);
}

// ---------------- workspace layout (bytes) ----------------
#define WQT_OFF 0         // ushort[576*192]  W_qkv^T bf16, Q rows pre-scaled
#define WOT_OFF 221184    // ushort[192*192]  W_out^T  bf16
#define BQ_OFF  294912    // float[576]       b_qkv, Q part pre-scaled
#define OWS_OFF 297216    // ushort[65536*192] attention output O, bf16
// layout of OWS: [(bw*2+hh)*64 + t][96]  (hh selects channel half)
// total 297216 + 25165824 = 25463040 bytes

// ================= prep: coalesced LDS-tiled transpose =================
__global__ void prep_kernel(const float* __restrict__ Wqkv,
                            const float* __restrict__ bqkv,
                            const float* __restrict__ Wout,
                            unsigned short* __restrict__ WqT,
                            unsigned short* __restrict__ WoT,
                            float* __restrict__ bq) {
    __shared__ float tile[32][33];
    const float SCALE = 0.17677669529663687f;  // 1/sqrt(32)
    int bid = blockIdx.x;
    int tx = threadIdx.x & 31, ty = threadIdx.x >> 5;
    if (bid < 108) {                       // W_qkv [192][576] -> WqT [576][192]
        int tn = bid % 18, tc = bid / 18;
#pragma unroll
        for (int i = 0; i < 4; ++i)
            tile[ty + i * 8][tx] = Wqkv[(tc * 32 + ty + i * 8) * 576 + tn * 32 + tx];
        __syncthreads();
        bool isQ = (tn < 6);
#pragma unroll
        for (int i = 0; i < 4; ++i) {
            float v = tile[tx][ty + i * 8];
            if (isQ) v *= SCALE;
            WqT[(tn * 32 + ty + i * 8) * 192 + tc * 32 + tx] = f2bf(v);
        }
    } else if (bid < 144) {                // W_out [192][192] -> WoT [192][192]
        int bb = bid - 108;
        int tn = bb % 6, tc = bb / 6;
#pragma unroll
        for (int i = 0; i < 4; ++i)
            tile[ty + i * 8][tx] = Wout[(tc * 32 + ty + i * 8) * 192 + tn * 32 + tx];
        __syncthreads();
#pragma unroll
        for (int i = 0; i < 4; ++i)
            WoT[(tn * 32 + ty + i * 8) * 192 + tc * 32 + tx] = f2bf(tile[tx][ty + i * 8]);
    } else {
        for (int i = threadIdx.x; i < 576; i += 256) {
            float v = bqkv[i];
            if (i < 192) v *= SCALE;
            bq[i] = v;
        }
    }
}

// ---------------- K1 LDS layout (ushort units) ----------------
// sX  [64][200] bf16 window input; aliased in phase 2 by per-wave P/O scratch
// sQK [64][200] bf16: Q cols 0..95 | K cols 96..191  (3 heads * 32)
// sVt [96][72]  bf16 V transposed [c][t]
// sRel float[1029] rel_params slice for 3 heads
#define OFF_X    0
#define OFF_QK   12800
#define OFF_VT   25600
#define OFF_RELF 32512     // float region starts here (ushort index)
#define SMEM_US  34570     // 69140 bytes -> 2 blocks/CU

__global__ __launch_bounds__(384, 3) void wmsa_kernel(
    const float* __restrict__ x, const float* __restrict__ rel,
    const unsigned short* __restrict__ WqT,
    const float* __restrict__ bq,
    unsigned short* __restrict__ Ows) {
    __shared__ __align__(16) unsigned short smem[SMEM_US];
    float* sRel = (float*)&smem[OFF_RELF];

    const int tid = threadIdx.x;
    const int bid = blockIdx.x;            // (b, w, hh)
    const int hh  = bid & 1;               // head-half: heads hh*3 .. hh*3+2
    const int bw  = bid >> 1;
    const int b   = bw >> 9;
    const int w   = bw & 511;
    const int wz = w >> 6, wy = (w >> 3) & 7, wx = w & 7;

    // ---------- phase 0: rel slice + x window (fp32 -> bf16 LDS) ----------
    for (int i = tid; i < 1029; i += 384) sRel[i] = rel[hh * 1029 + i];
#pragma unroll
    for (int p = 0; p < 4; ++p) {
        int f = p * 3072 + tid * 8;        // 12288 floats total, 8 per thread/pass
        int t = f / 192, c = f - t * 192;
        int tz = t >> 4, ty = (t >> 2) & 3, tx = t & 3;
        int gz = (wz * 4 + tz + 2) & 31;   // roll(-2) folded in
        int gy = (wy * 4 + ty + 2) & 31;
        int gx = (wx * 4 + tx + 2) & 31;
        const float* xp = x + ((((b * 32 + gz) * 32 + gy) * 32 + gx)) * 192 + c;
        float4 v0 = *(const float4*)xp;
        float4 v1 = *(const float4*)(xp + 4);
        us8 pk;
        pk[0] = f2bf(v0.x); pk[1] = f2bf(v0.y); pk[2] = f2bf(v0.z); pk[3] = f2bf(v0.w);
        pk[4] = f2bf(v1.x); pk[5] = f2bf(v1.y); pk[6] = f2bf(v1.z); pk[7] = f2bf(v1.w);
        *(us8*)&smem[OFF_X + t * 200 + c] = pk;
    }
    __syncthreads();

    const int lane = tid & 63;
    const int wv   = tid >> 6;     // wave id 0..5
    const int g    = lane >> 4;    // quad id 0..3
    const int l15  = lane & 15;

    // ---------- phase 1: QKV (3 heads) = Xw(64x192) @ W^T -> 64x288 ----------
    // 18 n-blocks over 6 waves = 3 each
#pragma unroll
    for (int j = 0; j < 3; ++j) {
        int nb = wv + j * 6;
        int nglob = (nb < 6)  ? (hh * 96 + nb * 16)
                  : (nb < 12) ? (192 + hh * 96 + (nb - 6) * 16)
                              : (384 + hh * 96 + (nb - 12) * 16);
        float bias = bq[nglob + l15];
        bf16x8 bfr[6];
        const unsigned short* wp = WqT + (nglob + l15) * 192 + g * 8;
#pragma unroll
        for (int kk = 0; kk < 6; ++kk) bfr[kk] = *(const bf16x8*)(wp + kk * 32);
#pragma unroll
        for (int m = 0; m < 4; ++m) {
            f32x4 acc = {bias, bias, bias, bias};
#pragma unroll
            for (int kk = 0; kk < 6; ++kk) {
                bf16x8 afr = *(const bf16x8*)&smem[OFF_X + (m * 16 + l15) * 200 + kk * 32 + g * 8];
                acc = MFMA16(afr, bfr[kk], acc);
            }
            int row0 = m * 16 + g * 4;
            if (nb < 12) {                    // Q (cols 0..95) / K (cols 96..191)
                int colg = nb * 16 + l15;
#pragma unroll
                for (int r = 0; r < 4; ++r)
                    smem[OFF_QK + (row0 + r) * 200 + colg] = f2bf(acc[r]);
            } else {                          // V -> sVt[c][t]
                int cl = (nb - 12) * 16 + l15;
                us4 pk;
#pragma unroll
                for (int r = 0; r < 4; ++r) pk[r] = f2bf(acc[r]);
                *(us4*)&smem[OFF_VT + cl * 72 + row0] = pk;
            }
        }
    }
    __syncthreads();

    // ---------- phase 2: attention, 12 iterations (3 heads x 4 mb) / 6 waves ----------
    const bool sz = (wz == 7), sy = (wy == 7), sx = (wx == 7);
    {
        const int qy = (l15 >> 2) & 3, qx = l15 & 3;
        unsigned short* pb = &smem[OFF_X + wv * 1152];   // per-wave scratch (aliases sX)
#pragma unroll
        for (int ii = 0; ii < 2; ++ii) {
            int it = wv * 2 + ii;
            int h3 = it >> 2, mb = it & 3;
            bf16x8 qf = *(const bf16x8*)&smem[OFF_QK + (mb * 16 + l15) * 200 + h3 * 32 + g * 8];
            f32x4 s[4];
#pragma unroll
            for (int f = 0; f < 4; ++f) {
                bf16x8 kf = *(const bf16x8*)&smem[OFF_QK + (f * 16 + l15) * 200 + 96 + h3 * 32 + g * 8];
                f32x4 z = {0.f, 0.f, 0.f, 0.f};
                s[f] = MFMA16(qf, kf, z);
            }
            // bias + shift mask.  p=(mb,g,r), q=(f,qy,qx)
#pragma unroll
            for (int f = 0; f < 4; ++f) {
                bool mz = sz && ((mb < 2) != (f < 2));
                bool my = sy && ((g < 2) != (qy < 2));
                int base = h3 * 343 + (mb - f + 3) * 49 + (g - qy + 3) * 7 + (3 - qx);
#pragma unroll
                for (int r = 0; r < 4; ++r) {
                    float v = s[f][r] + sRel[base + r];
                    bool mx = sx && ((r < 2) != (qx < 2));
                    s[f][r] = (mz | my | mx) ? -1e30f : v;
                }
            }
            // softmax per row (row = mb*16 + g*4 + r)
#pragma unroll
            for (int r = 0; r < 4; ++r) {
                float m0 = fmaxf(fmaxf(s[0][r], s[1][r]), fmaxf(s[2][r], s[3][r]));
#pragma unroll
                for (int d = 1; d < 16; d <<= 1) m0 = fmaxf(m0, __shfl_xor(m0, d, 64));
                float p0 = __expf(s[0][r] - m0);
                float p1 = __expf(s[1][r] - m0);
                float p2 = __expf(s[2][r] - m0);
                float p3 = __expf(s[3][r] - m0);
                float sm = p0 + p1 + p2 + p3;
#pragma unroll
                for (int d = 1; d < 16; d <<= 1) sm += __shfl_xor(sm, d, 64);
                float inv = 1.0f / sm;
                s[0][r] = p0 * inv; s[1][r] = p1 * inv;
                s[2][r] = p2 * inv; s[3][r] = p3 * inv;
            }
            // P (C-layout) -> per-wave LDS -> A-frags (same wave, no barrier)
#pragma unroll
            for (int f = 0; f < 4; ++f)
#pragma unroll
                for (int r = 0; r < 4; ++r)
                    pb[(g * 4 + r) * 72 + f * 16 + l15] = f2bf(s[f][r]);
            // PV: O(16x32) = P(16x64) @ V(64x32)
            f32x4 o0 = {0.f, 0.f, 0.f, 0.f}, o1 = {0.f, 0.f, 0.f, 0.f};
#pragma unroll
            for (int kt = 0; kt < 2; ++kt) {
                bf16x8 pf = *(const bf16x8*)&pb[l15 * 72 + kt * 32 + g * 8];
                bf16x8 v0 = *(const bf16x8*)&smem[OFF_VT + (h3 * 32 + l15) * 72 + kt * 32 + g * 8];
                bf16x8 v1 = *(const bf16x8*)&smem[OFF_VT + (h3 * 32 + 16 + l15) * 72 + kt * 32 + g * 8];
                o0 = MFMA16(pf, v0, o0);
                o1 = MFMA16(pf, v1, o1);
            }
            // O tile (16x32) -> scratch -> coalesced bf16 store to Ows
#pragma unroll
            for (int r = 0; r < 4; ++r) {
                pb[(g * 4 + r) * 32 + l15]      = f2bf(o0[r]);
                pb[(g * 4 + r) * 32 + 16 + l15] = f2bf(o1[r]);
            }
            us8 pk = *(const us8*)&pb[(lane >> 2) * 32 + (lane & 3) * 8];
            *(us8*)&Ows[(bid * 64 + mb * 16 + (lane >> 2)) * 96 + h3 * 32 + (lane & 3) * 8] = pk;
        }
    }
}

// ================= K2: out = O(65536x192) @ WoutT^T + b_out, un-window + roll =================
__global__ __launch_bounds__(256) void oproj_kernel(
    const unsigned short* __restrict__ Ows,
    const unsigned short* __restrict__ WoT,
    const float* __restrict__ bout, float* __restrict__ out) {
    const int bw = blockIdx.x;             // window tile: 64 rows
    const int b  = bw >> 9;
    const int w  = bw & 511;
    const int wz = w >> 6, wy = (w >> 3) & 7, wx = w & 7;
    const int lane = threadIdx.x & 63;
    const int wv   = threadIdx.x >> 6;     // m-block 0..3 (16 rows each)
    const int g    = lane >> 4;
    const int l15  = lane & 15;

    bf16x8 af[6];
#pragma unroll
    for (int kk = 0; kk < 6; ++kk) {
        int hh = (kk >= 3) ? 1 : 0;
        af[kk] = *(const bf16x8*)&Ows[(((bw << 1) | hh) * 64 + wv * 16 + l15) * 96 + (kk - hh * 3) * 32 + g * 8];
    }
    const int gz = (wz * 4 + wv + 2) & 31;   // token t = wv*16 + g*4 + r; roll(+2)
    const int gy = (wy * 4 + g + 2) & 31;
#pragma unroll
    for (int nb = 0; nb < 12; ++nb) {
        float bo = bout[nb * 16 + l15];
        const unsigned short* wp = WoT + (nb * 16 + l15) * 192 + g * 8;
        bf16x8 bf[6];
#pragma unroll
        for (int kk = 0; kk < 6; ++kk) bf[kk] = *(const bf16x8*)(wp + kk * 32);
        f32x4 acc = {bo, bo, bo, bo};
#pragma unroll
        for (int kk = 0; kk < 6; ++kk) acc = MFMA16(af[kk], bf[kk], acc);
        int col = nb * 16 + l15;
#pragma unroll
        for (int r = 0; r < 4; ++r) {
            int gx = (wx * 4 + r + 2) & 31;
            out[(((b * 32 + gz) * 32 + gy) * 32 + gx) * 192 + col] = acc[r];
        }
    }
}

extern "C" void kernel_launch(void* const* d_in, const int* in_sizes, int n_in,
                              void* d_out, int out_size, void* d_ws, size_t ws_size,
                              hipStream_t stream) {
    const float* x    = (const float*)d_in[0];
    const float* Wqkv = (const float*)d_in[1];
    const float* bqkv = (const float*)d_in[2];
    const float* rel  = (const float*)d_in[3];
    const float* Wout = (const float*)d_in[4];
    const float* bout = (const float*)d_in[5];

    unsigned short* WqT = (unsigned short*)((char*)d_ws + WQT_OFF);
    unsigned short* WoT = (unsigned short*)((char*)d_ws + WOT_OFF);
    float*          bq  = (float*)((char*)d_ws + BQ_OFF);
    unsigned short* Ows = (unsigned short*)((char*)d_ws + OWS_OFF);
    float*          out = (float*)d_out;

    prep_kernel<<<145, 256, 0, stream>>>(Wqkv, bqkv, Wout, WqT, WoT, bq);
    wmsa_kernel<<<2048, 384, 0, stream>>>(x, rel, WqT, bq, Ows);
    oproj_kernel<<<1024, 256, 0, stream>>>(Ows, WoT, bout, out);
}